// Round 12
// baseline (25.204 us; speedup 1.0000x reference)
//
#include <hip/hip_runtime.h>

#define BB 16
#define NN 6000
#define GG 512
#define WAVES 16
#define RPT 6
#define RPB (RPT * 64)   // 384 ROIs/block; grid.x = 16 -> 256 blocks = 1/CU

__device__ __forceinline__ int rfl(int v) { return __builtin_amdgcn_readfirstlane(v); }

__global__ __launch_bounds__(64 * WAVES) void det_kernel(
    const float4* __restrict__ rois,      // (B, N, 4)
    const int*    __restrict__ gt_ids,    // (B, G)
    const float4* __restrict__ gt_boxes,  // (B, G, 4)
    float*        __restrict__ out)       // [B*2*N maxes][B*N pos][B*N neg]
{
    __shared__ float4 s_box[GG];             // nc from front, crowd from back
    __shared__ float4 s_area4[GG / 4];
    __shared__ float  s_ncm[WAVES][RPB];
    __shared__ float  s_cm[WAVES][RPB];
    __shared__ float  s_val[RPB];
    __shared__ int    s_wn[8], s_wc[8];      // per-wave popcounts (waves 0-7 own GTs)
    float* s_area = (float*)s_area4;

    const int b    = blockIdx.y;
    const int tid  = threadIdx.x;
    const int wave = tid >> 6;
    const int lane = tid & 63;

    // ---- issue ROI loads early ----
    const int nbase = blockIdx.x * RPB;
    float4 r[RPT];
    float  rs[RPT];
    #pragma unroll
    for (int i = 0; i < RPT; ++i) {
        int n = nbase + i * 64 + lane;
        r[i] = (n < NN) ? rois[b * NN + n] : make_float4(0.f, 0.f, 0.f, 0.f);
    }
    #pragma unroll
    for (int i = 0; i < RPT; ++i) {
        rs[i] = (r[i].z - r[i].x) * (r[i].w - r[i].y) + 1e-8f;
        if (wave == 0)
            s_val[i * 64 + lane] =
                ((fabsf(r[i].x) + fabsf(r[i].y) + fabsf(r[i].z) + fabsf(r[i].w)) > 0.f) ? 1.f : 0.f;
    }

    // ---- ballot compaction: waves 0-7 own one GT per thread ----
    bool pn = false, pc = false;
    float4 box;
    unsigned long long mn = 0, mc = 0;
    if (wave < 8) {
        box = gt_boxes[b * GG + tid];
        const int id = gt_ids[b * GG + tid];
        const float asum = fabsf(box.x) + fabsf(box.y) + fabsf(box.z) + fabsf(box.w);
        pn = (asum > 0.0f) && (id > 0);
        pc = (asum > 0.0f) && (id < 0);
        mn = __ballot(pn);
        mc = __ballot(pc);
        if (lane == 0) { s_wn[wave] = __popcll(mn); s_wc[wave] = __popcll(mc); }
    }
    __syncthreads();

    int bn = 0, bc = 0, ncnt = 0, ccnt = 0;
    #pragma unroll
    for (int w = 0; w < 8; ++w) {
        int pw = s_wn[w], cw = s_wc[w];
        if (w < wave) { bn += pw; bc += cw; }
        ncnt += pw; ccnt += cw;
    }
    const int lo = GG - ccnt;
    int nc_eff = (ncnt + 3) & ~3;          // pad nc list up to x4
    int lo_pad = lo & ~3;                  // pad crowd list down to x4
    if (nc_eff > lo_pad) nc_eff = lo_pad;

    if (wave < 8) {
        const unsigned long long lt = (1ULL << lane) - 1ULL;
        if (pn) {
            int idx = bn + __popcll(mn & lt);
            s_box[idx]  = box;
            s_area[idx] = (box.z - box.x) * (box.w - box.y);
        }
        if (pc) {
            int idx = (GG - 1) - (bc + __popcll(mc & lt));
            s_box[idx]  = box;
            s_area[idx] = (box.z - box.x) * (box.w - box.y);
        }
    }
    // zero-fill pad slots (zero box => t=0, harmless for max)
    {
        const float4 z = make_float4(0.f, 0.f, 0.f, 0.f);
        if (tid < 4) {
            int i = ncnt + tid;
            if (i < nc_eff) { s_box[i] = z; s_area[i] = 0.f; }
        } else if (tid < 8) {
            int i = lo_pad + (tid - 4);
            if (i < lo) { s_box[i] = z; s_area[i] = 0.f; }
        }
    }
    __syncthreads();

    // t = inter * rcp(rarea + garea + eps)  (monotone in IoU)
    auto tval = [](const float4& rr, float rsum, const float4& g4, float ga) -> float {
        float dy = fminf(rr.z, g4.z) - fmaxf(rr.x, g4.x);
        float dx = fminf(rr.w, g4.w) - fmaxf(rr.y, g4.y);
        float inter = fmaxf(fmaxf(dy, 0.f) * dx, 0.f);
        return inter * __builtin_amdgcn_rcpf(rsum + ga);
    };

    float anc[RPT] = {0.f, 0.f, 0.f, 0.f, 0.f, 0.f};
    float ac[RPT]  = {0.f, 0.f, 0.f, 0.f, 0.f, 0.f};

    // Software-pipelined, wave-strided group loop (stride = WAVES).
    auto run = [&](int q0, int qend, float* acc) {
        if (q0 >= qend) return;
        float4 nb0 = s_box[4 * q0 + 0];
        float4 nb1 = s_box[4 * q0 + 1];
        float4 nb2 = s_box[4 * q0 + 2];
        float4 nb3 = s_box[4 * q0 + 3];
        float4 na  = s_area4[q0];
        for (int q = q0; q < qend; q += WAVES) {
            const float4 cb0 = nb0, cb1 = nb1, cb2 = nb2, cb3 = nb3, ca = na;
            const int qn = (q + WAVES < qend) ? q + WAVES : q0;   // wrap: last prefetch unused
            nb0 = s_box[4 * qn + 0];
            nb1 = s_box[4 * qn + 1];
            nb2 = s_box[4 * qn + 2];
            nb3 = s_box[4 * qn + 3];
            na  = s_area4[qn];
            #pragma unroll
            for (int i = 0; i < RPT; ++i) {
                float t0 = tval(r[i], rs[i], cb0, ca.x);
                float t1 = tval(r[i], rs[i], cb1, ca.y);
                float t2 = tval(r[i], rs[i], cb2, ca.z);
                float t3 = tval(r[i], rs[i], cb3, ca.w);
                acc[i] = fmaxf(acc[i], fmaxf(fmaxf(t0, t1), fmaxf(t2, t3)));
            }
        }
    };

    // ---- non-crowd: groups [0, nc_eff/4), strided across 16 waves ----
    {
        const int ngr = rfl(nc_eff >> 2);
        run(wave, ngr, anc);
    }
    // ---- crowd: groups [lo_pad/4, GG/4), strided across 16 waves ----
    {
        const int cg0 = rfl(lo_pad >> 2);
        run(cg0 + wave, GG >> 2, ac);
    }

    #pragma unroll
    for (int i = 0; i < RPT; ++i) {
        s_ncm[wave][i * 64 + lane] = anc[i];
        s_cm[wave][i * 64 + lane]  = ac[i];
    }
    __syncthreads();

    // ---- reduce across waves; threads 0..RPB-1 own one ROI slot each ----
    if (tid < RPB) {
        const int n = nbase + tid;
        if (n < NN) {
            float a = s_ncm[0][tid], c = s_cm[0][tid];
            #pragma unroll
            for (int w = 1; w < WAVES; ++w) {
                a = fmaxf(a, s_ncm[w][tid]);
                c = fmaxf(c, s_cm[w][tid]);
            }
            const float vr = s_val[tid];           // 1.0 or 0.0
            a *= vr;
            c *= vr;
            // t -> iou: iou = t/(1-t); t in [0, 0.5] so well-conditioned
            const float nc_max = a * __builtin_amdgcn_rcpf(1.f - a);
            const float c_max  = c * __builtin_amdgcn_rcpf(1.f - c);

            out[b * 2 * NN + n]      = nc_max;     // iou_maxes (B,2,N) ch0
            out[b * 2 * NN + NN + n] = c_max;      // iou_maxes (B,2,N) ch1
            const float pos = (vr > 0.f && nc_max >= 0.5f) ? 1.0f : 0.0f;
            const float neg = (vr > 0.f && nc_max < 0.5f && c_max < 0.001f) ? 1.0f : 0.0f;
            out[BB * 2 * NN + b * NN + n]           = pos;
            out[BB * 2 * NN + BB * NN + b * NN + n] = neg;
        }
    }
}

extern "C" void kernel_launch(void* const* d_in, const int* in_sizes, int n_in,
                              void* d_out, int out_size, void* d_ws, size_t ws_size,
                              hipStream_t stream) {
    const float4* rois     = (const float4*)d_in[0];
    const int*    gt_ids   = (const int*)d_in[1];
    const float4* gt_boxes = (const float4*)d_in[2];
    float*        out      = (float*)d_out;

    dim3 grid((NN + RPB - 1) / RPB, BB);   // 16 x 16 = 256 blocks = exactly 1/CU
    det_kernel<<<grid, 64 * WAVES, 0, stream>>>(rois, gt_ids, gt_boxes, out);
}